// Round 2
// baseline (546.670 us; speedup 1.0000x reference)
//
#include <hip/hip_runtime.h>
#include <stdint.h>

typedef short bf16x8 __attribute__((ext_vector_type(8)));
typedef float f32x4 __attribute__((ext_vector_type(4)));

#define HID 128
#define TT 32
#define HWSZ 1024
#define PX 32
#define NTHREADS 512

__device__ __forceinline__ float bf2f(unsigned short u) {
    union { unsigned int i; float f; } v; v.i = ((unsigned int)u) << 16; return v.f;
}
__device__ __forceinline__ unsigned short f2bf(float f) {
    union { float f; unsigned int i; } v; v.f = f;
    unsigned int u = v.i;
    return (unsigned short)((u + 0x7fffu + ((u >> 16) & 1u)) >> 16);
}
__device__ __forceinline__ float sigmoidf_(float x) { return 1.0f / (1.0f + __expf(-x)); }
__device__ __forceinline__ float tanhf_(float x)    { return 2.0f / (1.0f + __expf(-2.0f * x)) - 1.0f; }

// One block owns PX=32 pixels for the whole sequence. 8 waves; wave w owns
// hidden channels [16w,16w+16) across all 4 gates -> in-register LSTM
// pointwise, no cross-wave gate exchange. Weights (fp32 in HBM) are converted
// once to bf16 MFMA B-fragments held in VGPRs (loop-invariant over t).
// LDS row per pixel: [ x_t bf16 (CIN) | h buf0 (128) | h buf1 (128) | pad 8 ].
// IN_BF16 / OUT_BF16 select fp32 vs packed-bf16 global I/O for the
// inter-layer activation (bf16 scratch in d_ws when it fits).
template <int CIN, bool FINAL, bool IN_BF16, bool OUT_BF16>
__global__ __launch_bounds__(NTHREADS, 2)
void lstm_layer(const void* in_,
                const float* __restrict__ W,
                const float* __restrict__ bias,
                void* y_,
                float* hT,
                float* cT)
{
    constexpr int K      = CIN + HID;         // 192 or 256
    constexpr int XK     = CIN / 32;          // x-part k-iters
    constexpr int KITERS = K / 32;            // 6 or 8
    constexpr int PITCH  = CIN + 2 * HID + 8; // rows 16B-aligned; dword-stride 4 mod 32
                                              // -> b128 reads hit all 32 banks uniformly

    const float* inF          = (const float*)in_;
    const unsigned short* inB = (const unsigned short*)in_;
    float* yF                 = (float*)y_;
    unsigned short* yB        = (unsigned short*)y_;

    __shared__ __align__(16) unsigned short z[PX][PITCH];

    const int tid  = threadIdx.x;
    const int wave = tid >> 6;
    const int lane = tid & 63;
    const int q    = lane >> 4;   // k-quad of this lane in A/B frags
    const int ln   = lane & 15;   // m (A) / n (B) index

    const int p0  = blockIdx.x * PX;
    const int b   = p0 >> 10;
    const int hw0 = p0 & 1023;    // multiple of 32

    // ---- preload B fragments: B[k][n] = W[n][k], n = gate row = g*128 + 16*wave + ln
    bf16x8 Bf[KITERS][4];
    #pragma unroll
    for (int k = 0; k < KITERS; ++k) {
        #pragma unroll
        for (int g = 0; g < 4; ++g) {
            const int row = g * HID + wave * 16 + ln;
            const float* wp = W + row * K + k * 32 + q * 8;
            bf16x8 v;
            #pragma unroll
            for (int j = 0; j < 8; ++j) v[j] = (short)f2bf(wp[j]);
            Bf[k][g] = v;
        }
    }
    const int ch = wave * 16 + ln;           // this lane's hidden channel
    const float bi  = bias[0 * HID + ch];
    const float bf_ = bias[1 * HID + ch];
    const float bo  = bias[2 * HID + ch];
    const float bg  = bias[3 * HID + ch];

    // zero h buffer 0 (used at t=0); disjoint from phase-1's x region
    #pragma unroll
    for (int idx = tid; idx < PX * HID; idx += NTHREADS)
        z[idx & (PX - 1)][CIN + (idx >> 5)] = 0;

    float cst[2][4];
    #pragma unroll
    for (int mt = 0; mt < 2; ++mt)
        #pragma unroll
        for (int r = 0; r < 4; ++r) cst[mt][r] = 0.0f;

    for (int t = 0; t < TT; ++t) {
        // ---- phase 1: stage x_t -> z[px][c] as bf16 (coalesced 32-elem px-runs)
        const int inbase = (b * TT + t) * CIN * HWSZ + hw0;
        #pragma unroll
        for (int idx = tid; idx < PX * CIN; idx += NTHREADS) {
            const int px = idx & (PX - 1);
            const int c  = idx >> 5;
            const int off = inbase + c * HWSZ + px;
            z[px][c] = IN_BF16 ? inB[off] : f2bf(inF[off]);
        }
        __syncthreads();

        const int hoff_r = CIN + ((t & 1) ? HID : 0);  // h used by this step's GEMM
        const int hoff_w = CIN + ((t & 1) ? 0 : HID);  // h produced by this step

        // ---- phase 2: gates[32 px, 512] = z @ W^T  (A from LDS, B from regs)
        f32x4 acc[2][4];
        #pragma unroll
        for (int mt = 0; mt < 2; ++mt)
            #pragma unroll
            for (int g = 0; g < 4; ++g)
                acc[mt][g] = (f32x4){0.f, 0.f, 0.f, 0.f};

        #pragma unroll
        for (int k = 0; k < KITERS; ++k) {
            const int koff = (k < XK) ? (k * 32) : (hoff_r + (k - XK) * 32);
            const bf16x8 a0 = *(const bf16x8*)(&z[ln][koff + q * 8]);
            const bf16x8 a1 = *(const bf16x8*)(&z[16 + ln][koff + q * 8]);
            #pragma unroll
            for (int g = 0; g < 4; ++g) {
                acc[0][g] = __builtin_amdgcn_mfma_f32_16x16x32_bf16(a0, Bf[k][g], acc[0][g], 0, 0, 0);
                acc[1][g] = __builtin_amdgcn_mfma_f32_16x16x32_bf16(a1, Bf[k][g], acc[1][g], 0, 0, 0);
            }
        }

        // ---- phase 3: LSTM pointwise; C/D layout: n = lane&15, m = (lane>>4)*4 + reg
        #pragma unroll
        for (int mt = 0; mt < 2; ++mt) {
            #pragma unroll
            for (int r = 0; r < 4; ++r) {
                const int px = mt * 16 + q * 4 + r;
                const float iv = sigmoidf_(acc[mt][0][r] + bi);
                const float fv = sigmoidf_(acc[mt][1][r] + bf_);
                const float ov = sigmoidf_(acc[mt][2][r] + bo);
                const float gv = tanhf_(acc[mt][3][r] + bg);
                const float c  = fv * cst[mt][r] + iv * gv;
                cst[mt][r] = c;
                const float h = ov * tanhf_(c);
                z[px][hoff_w + ch] = f2bf(h);
                if (FINAL && t == TT - 1)
                    cT[(b * HID + ch) * HWSZ + hw0 + px] = c;
            }
        }
        __syncthreads();

        // ---- phase 4: write y_t from LDS (coalesced px-runs)
        const int ybase = (b * TT + t) * HID * HWSZ + hw0;
        #pragma unroll
        for (int idx = tid; idx < PX * HID; idx += NTHREADS) {
            const int px = idx & (PX - 1);
            const int c  = idx >> 5;
            const unsigned short v = z[px][hoff_w + c];
            const int off = ybase + c * HWSZ + px;
            if (OUT_BF16) yB[off] = v; else yF[off] = bf2f(v);
            if (FINAL && t == TT - 1)
                hT[(b * HID + c) * HWSZ + hw0 + px] = bf2f(v);
        }
    }
}

extern "C" void kernel_launch(void* const* d_in, const int* in_sizes, int n_in,
                              void* d_out, int out_size, void* d_ws, size_t ws_size,
                              hipStream_t stream) {
    const float* x  = (const float*)d_in[0];
    const float* W0 = (const float*)d_in[1];
    const float* b0 = (const float*)d_in[2];
    const float* W1 = (const float*)d_in[3];
    const float* b1 = (const float*)d_in[4];
    float* out = (float*)d_out;

    float* y  = out;                      // [8,32,128,32,32] fp32
    float* hT = out + 33554432;           // [8,128,32,32] fp32
    float* cT = out + 34603008;           // [8,128,32,32] fp32

    dim3 grid(8192 / PX), block(NTHREADS);

    // layer-0 output y0: bf16 scratch in d_ws when it fits (67 MB), else
    // fp32 in-place in the y region (same block reads t before writing t).
    const size_t y0_bf16_bytes = (size_t)8 * TT * HID * HWSZ * 2;  // 67108864
    if (ws_size >= y0_bf16_bytes) {
        unsigned short* y0 = (unsigned short*)d_ws;
        lstm_layer<64,  false, false, true ><<<grid, block, 0, stream>>>(x,  W0, b0, y0, nullptr, nullptr);
        lstm_layer<128, true,  true,  false><<<grid, block, 0, stream>>>(y0, W1, b1, y,  hT, cT);
    } else {
        lstm_layer<64,  false, false, false><<<grid, block, 0, stream>>>(x, W0, b0, y, nullptr, nullptr);
        lstm_layer<128, true,  false, false><<<grid, block, 0, stream>>>(y, W1, b1, y, hT, cT);
    }
}

// Round 3
// 356.974 us; speedup vs baseline: 1.5314x; 1.5314x over previous
//
#include <hip/hip_runtime.h>

typedef short bf16x8 __attribute__((ext_vector_type(8)));
typedef short bf16x4 __attribute__((ext_vector_type(4)));
typedef float f32x4  __attribute__((ext_vector_type(4)));

#define HID 128
#define TT 32
#define HWSZ 1024
#define PX 32
#define NTHREADS 512

__device__ __forceinline__ float bf2f(unsigned short u) {
    union { unsigned int i; float f; } v; v.i = ((unsigned int)u) << 16; return v.f;
}
__device__ __forceinline__ unsigned short f2bf(float f) {
    union { float f; unsigned int i; } v; v.f = f;
    unsigned int u = v.i;
    return (unsigned short)((u + 0x7fffu + ((u >> 16) & 1u)) >> 16);
}
__device__ __forceinline__ float frcp(float x) { return __builtin_amdgcn_rcpf(x); }
__device__ __forceinline__ float sigm(float x) { return frcp(1.0f + __expf(-x)); }
__device__ __forceinline__ float ftanh(float x){ return 1.0f - 2.0f * frcp(1.0f + __expf(2.0f * x)); }

// One block = PX=32 pixels for the whole sequence; 8 waves; wave w owns
// hidden channels [16w,16w+16) x 4 gates. MFMA operands: A = W rows (m=gate
// row), B = pixel rows (n=px)  ->  D reg-dim = channel: lane owns 4
// consecutive channels -> packed b64 h-writeback, float4 bias, coalesced cT.
// Single barrier per step: x_{t+1} prefetched to regs during GEMM; x and h
// double-buffered in LDS.
// LDS row (per px): [x0 CIN | x1 CIN | h0 HID | h1 HID | pad 8].
// IN_LOCAL/OUT_LOCAL: inter-layer activation in block-local bf16 scratch
// [block][t][px][c] (16B/thread chunks, no partial-line RMW).
template <int CIN, bool FINAL, bool IN_LOCAL, bool OUT_LOCAL>
__global__ __launch_bounds__(NTHREADS, 2)
void lstm_layer(const void* __restrict__ in_, const float* __restrict__ W,
                const float* __restrict__ bias, void* __restrict__ y_,
                float* __restrict__ hT, float* __restrict__ cT)
{
    constexpr int K      = CIN + HID;
    constexpr int XK     = CIN / 32;
    constexpr int KITERS = K / 32;
    constexpr int XB0 = 0, XB1 = CIN, HB0 = 2 * CIN, HB1 = 2 * CIN + HID;
    constexpr int PITCH = 2 * CIN + 2 * HID + 8;       // bytes/row mult. of 16
    constexpr int NIT = (PX * CIN / 4) / NTHREADS;     // fp32-in iters (1 or 2)

    const float* inF          = (const float*)in_;
    const unsigned short* inL = (const unsigned short*)in_;
    float* yF                 = (float*)y_;
    unsigned short* yL        = (unsigned short*)y_;

    __shared__ __align__(16) unsigned short z[PX][PITCH];

    const int tid  = threadIdx.x;
    const int wave = tid >> 6;
    const int lane = tid & 63;
    const int q    = lane >> 4;
    const int ln   = lane & 15;

    const int p0  = blockIdx.x * PX;
    const int b   = p0 >> 10;
    const int hw0 = p0 & 1023;

    const long long locbase = (long long)blockIdx.x * TT * PX * HID;  // local scratch
    const long long inFbase = (long long)b * TT * CIN * HWSZ + hw0;   // fp32 [c][hw]

    // ---- preload W fragments (A operand): A[m=ln][k=q*8+j], rows = gate tiles
    bf16x8 Af[KITERS][4];
    #pragma unroll
    for (int k = 0; k < KITERS; ++k) {
        #pragma unroll
        for (int g = 0; g < 4; ++g) {
            const float* wp = W + (g * HID + wave * 16 + ln) * K + k * 32 + q * 8;
            bf16x8 v;
            #pragma unroll
            for (int j = 0; j < 8; ++j) v[j] = (short)f2bf(wp[j]);
            Af[k][g] = v;
        }
    }
    // bias: lane's 4 consecutive channels per gate
    f32x4 bs[4];
    #pragma unroll
    for (int g = 0; g < 4; ++g)
        bs[g] = *(const f32x4*)(bias + g * HID + wave * 16 + q * 4);

    const int ch0 = wave * 16 + q * 4;   // lane's first channel

    // ---- zero h buf0; stage x_0 into x buf0
    #pragma unroll
    for (int idx = tid; idx < PX * HID; idx += NTHREADS)
        z[idx & (PX - 1)][HB0 + (idx >> 5)] = 0;
    if (IN_LOCAL) {
        bf16x8 v = *(const bf16x8*)(inL + locbase + tid * 8);
        *(bf16x8*)&z[tid >> 4][XB0 + (tid & 15) * 8] = v;
    } else {
        #pragma unroll
        for (int it = 0; it < NIT; ++it) {
            const int idx = tid + it * NTHREADS;
            const int px = idx & 31, c0 = (idx >> 5) * 4;
            bf16x4 v;
            #pragma unroll
            for (int j = 0; j < 4; ++j) v[j] = (short)f2bf(inF[inFbase + (c0 + j) * HWSZ + px]);
            *(bf16x4*)&z[px][XB0 + c0] = v;
        }
    }
    __syncthreads();

    float cst[2][4];
    #pragma unroll
    for (int mt = 0; mt < 2; ++mt)
        #pragma unroll
        for (int r = 0; r < 4; ++r) cst[mt][r] = 0.0f;

    #pragma unroll 2
    for (int t = 0; t < TT; ++t) {
        const int cur = t & 1;
        const int xb_r = cur ? XB1 : XB0, xb_w = cur ? XB0 : XB1;
        const int hb_r = cur ? HB1 : HB0, hb_w = cur ? HB0 : HB1;
        const int tn = (t + 1 < TT) ? (t + 1) : t;   // clamped prefetch

        // ---- prefetch x_{t+1} into regs (latency hidden behind GEMM)
        bf16x8 pfv;
        float pff[NIT][4];
        if (IN_LOCAL) {
            pfv = *(const bf16x8*)(inL + locbase + (long long)tn * PX * HID + tid * 8);
        } else {
            #pragma unroll
            for (int it = 0; it < NIT; ++it) {
                const int idx = tid + it * NTHREADS;
                const int px = idx & 31, c0 = (idx >> 5) * 4;
                #pragma unroll
                for (int j = 0; j < 4; ++j)
                    pff[it][j] = inF[inFbase + (long long)tn * CIN * HWSZ + (c0 + j) * HWSZ + px];
            }
        }

        // ---- GEMM: D[gate_row][px] — A=W frags (regs), B=pixels (LDS)
        f32x4 acc[2][4];
        #pragma unroll
        for (int mt = 0; mt < 2; ++mt)
            #pragma unroll
            for (int g = 0; g < 4; ++g) acc[mt][g] = (f32x4){0.f, 0.f, 0.f, 0.f};

        #pragma unroll
        for (int k = 0; k < KITERS; ++k) {
            const int koff = (k < XK) ? (xb_r + k * 32) : (hb_r + (k - XK) * 32);
            const bf16x8 p0v = *(const bf16x8*)&z[ln][koff + q * 8];
            const bf16x8 p1v = *(const bf16x8*)&z[16 + ln][koff + q * 8];
            #pragma unroll
            for (int g = 0; g < 4; ++g) {
                acc[0][g] = __builtin_amdgcn_mfma_f32_16x16x32_bf16(Af[k][g], p0v, acc[0][g], 0, 0, 0);
                acc[1][g] = __builtin_amdgcn_mfma_f32_16x16x32_bf16(Af[k][g], p1v, acc[1][g], 0, 0, 0);
            }
        }

        // ---- pointwise: lane owns ch0..ch0+3 at px = mt*16 + ln
        #pragma unroll
        for (int mt = 0; mt < 2; ++mt) {
            const int px = mt * 16 + ln;
            bf16x4 hv;
            #pragma unroll
            for (int r = 0; r < 4; ++r) {
                const float iv = sigm(acc[mt][0][r] + bs[0][r]);
                const float fv = sigm(acc[mt][1][r] + bs[1][r]);
                const float ov = sigm(acc[mt][2][r] + bs[2][r]);
                const float gv = ftanh(acc[mt][3][r] + bs[3][r]);
                const float c  = fv * cst[mt][r] + iv * gv;
                cst[mt][r] = c;
                const float h = ov * ftanh(c);
                hv[r] = (short)f2bf(h);
                if (FINAL && t == TT - 1)
                    cT[(b * HID + ch0 + r) * HWSZ + hw0 + px] = c;
            }
            *(bf16x4*)&z[px][hb_w + ch0] = hv;
        }

        // ---- write prefetched x into xb_w
        if (IN_LOCAL) {
            *(bf16x8*)&z[tid >> 4][xb_w + (tid & 15) * 8] = pfv;
        } else {
            #pragma unroll
            for (int it = 0; it < NIT; ++it) {
                const int idx = tid + it * NTHREADS;
                const int px = idx & 31, c0 = (idx >> 5) * 4;
                bf16x4 v;
                #pragma unroll
                for (int j = 0; j < 4; ++j) v[j] = (short)f2bf(pff[it][j]);
                *(bf16x4*)&z[px][xb_w + c0] = v;
            }
        }

        __syncthreads();   // the ONLY barrier per step

        // ---- emit y_t from hb_w (next iter only reads hb_w/xb_w, writes the
        //      opposite buffers -> no second barrier needed)
        if (FINAL || !OUT_LOCAL) {
            const int c = tid >> 2, px8 = (tid & 3) * 8;
            float f[8];
            #pragma unroll
            for (int j = 0; j < 8; ++j) f[j] = bf2f(z[px8 + j][hb_w + c]);
            float* yp = yF + (long long)(b * TT + t) * HID * HWSZ + c * HWSZ + hw0 + px8;
            *(f32x4*)yp       = (f32x4){f[0], f[1], f[2], f[3]};
            *(f32x4*)(yp + 4) = (f32x4){f[4], f[5], f[6], f[7]};
            if (FINAL && t == TT - 1) {
                float* hp = hT + (long long)(b * HID + c) * HWSZ + hw0 + px8;
                *(f32x4*)hp       = (f32x4){f[0], f[1], f[2], f[3]};
                *(f32x4*)(hp + 4) = (f32x4){f[4], f[5], f[6], f[7]};
            }
        } else {
            bf16x8 v = *(const bf16x8*)&z[tid >> 4][hb_w + (tid & 15) * 8];
            *(bf16x8*)(yL + locbase + (long long)t * PX * HID + tid * 8) = v;
        }
    }
}

extern "C" void kernel_launch(void* const* d_in, const int* in_sizes, int n_in,
                              void* d_out, int out_size, void* d_ws, size_t ws_size,
                              hipStream_t stream) {
    const float* x  = (const float*)d_in[0];
    const float* W0 = (const float*)d_in[1];
    const float* b0 = (const float*)d_in[2];
    const float* W1 = (const float*)d_in[3];
    const float* b1 = (const float*)d_in[4];
    float* out = (float*)d_out;

    float* y  = out;                      // [8,32,128,32,32] fp32
    float* hT = out + 33554432;           // [8,128,32,32]
    float* cT = out + 34603008;           // [8,128,32,32]

    dim3 grid(8192 / PX), block(NTHREADS);

    const size_t y0_bytes = (size_t)8 * HWSZ * TT * HID * 2;  // 67 MB block-local bf16
    if (ws_size >= y0_bytes) {
        unsigned short* y0 = (unsigned short*)d_ws;
        lstm_layer<64,  false, false, true ><<<grid, block, 0, stream>>>(x,  W0, b0, y0, nullptr, nullptr);
        lstm_layer<128, true,  true,  false><<<grid, block, 0, stream>>>(y0, W1, b1, y,  hT, cT);
    } else {
        // fallback: y0 fp32 [b][t][c][hw] in-place in the y region (same-block
        // read-before-write per element; layers are separate launches)
        lstm_layer<64,  false, false, false><<<grid, block, 0, stream>>>(x, W0, b0, y, nullptr, nullptr);
        lstm_layer<128, true,  false, false><<<grid, block, 0, stream>>>(y, W1, b1, y, hT, cT);
    }
}